// Round 7
// baseline (1060.849 us; speedup 1.0000x reference)
//
#include <hip/hip_runtime.h>
#include <math.h>

#define B_    32
#define C_    128
#define HW_   16384          // 128*128
#define NPIX  524288         // B_*HW_
#define EPSF  1e-5f
#define NBLK  1024u

__device__ __forceinline__ float wave_sum(float v) {
#pragma unroll
    for (int off = 32; off > 0; off >>= 1) v += __shfl_down(v, off, 64);
    return v;
}

__device__ __forceinline__ float stat_ld(const float* p) {
    return __hip_atomic_load(p, __ATOMIC_RELAXED, __HIP_MEMORY_SCOPE_AGENT);
}

// Monotonic grid barrier (no reset; counter zeroed by host memset each launch).
// Safe because all NBLK blocks are co-resident: __launch_bounds__(256,4) =>
// 4 blocks/CU x 256 CUs = 1024 = NBLK.
__device__ __forceinline__ void gbar(unsigned* ctr, unsigned goal) {
    __syncthreads();
    __threadfence();                       // publish this block's writes (device scope)
    if (threadIdx.x == 0) {
        __hip_atomic_fetch_add(ctr, 1u, __ATOMIC_ACQ_REL, __HIP_MEMORY_SCOPE_AGENT);
        while (__hip_atomic_load(ctr, __ATOMIC_ACQUIRE, __HIP_MEMORY_SCOPE_AGENT) < goal)
            __builtin_amdgcn_s_sleep(2);
    }
    __syncthreads();                       // all threads held until lane-0 observed goal
}

// Persistent fused kernel: phase1 (channel mean/max + BN1 stats) -> gbar ->
// phase2 (BN1 affine + 7x7x2 conv + BN2 stats) -> gbar ->
// phase3 (sigmoid(BN2(conv)) * x, reversed sweep, sigmoid hoisted per (b,hw)).
__global__ __launch_bounds__(256, 4) void k_fused(const float* __restrict__ x,
                                                  const float* __restrict__ cw,
                                                  const float* __restrict__ g1,
                                                  const float* __restrict__ be1,
                                                  const float* __restrict__ g2,
                                                  const float* __restrict__ be2,
                                                  float* __restrict__ feat,
                                                  float* __restrict__ convout,
                                                  float* __restrict__ stats,
                                                  unsigned* __restrict__ bar,
                                                  float* __restrict__ out) {
    const int tid  = blockIdx.x * 256 + threadIdx.x;   // 262144 threads
    const int lane = threadIdx.x & 63, wid = threadIdx.x >> 6;

    __shared__ float red[4];
    __shared__ float w_s[98];
    __shared__ float sc_s[2], sh_s[2];

    // ---------------- Phase 1: per-pixel channel mean/max over C=128 ----------------
    {
        int pg  = (blockIdx.x * 4 + wid) * 32 + (lane & 31);  // 131072 float4-pixel groups
        int b   = pg >> 12;
        int hw  = (pg & 4095) << 2;
        int ch0 = (lane >> 5) * 64;                           // lanes 0-31: ch 0-63; 32-63: 64-127

        const float4* xp = reinterpret_cast<const float4*>(
            x + (size_t)b * C_ * HW_ + (size_t)ch0 * HW_ + hw);
        float4 s = make_float4(0.f, 0.f, 0.f, 0.f);
        float4 m = make_float4(-INFINITY, -INFINITY, -INFINITY, -INFINITY);
#pragma unroll 8
        for (int c = 0; c < 64; ++c) {
            float4 v = xp[(size_t)c * (HW_ / 4)];
            s.x += v.x; s.y += v.y; s.z += v.z; s.w += v.w;
            m.x = fmaxf(m.x, v.x); m.y = fmaxf(m.y, v.y);
            m.z = fmaxf(m.z, v.z); m.w = fmaxf(m.w, v.w);
        }
        s.x += __shfl_xor(s.x, 32, 64); s.y += __shfl_xor(s.y, 32, 64);
        s.z += __shfl_xor(s.z, 32, 64); s.w += __shfl_xor(s.w, 32, 64);
        m.x = fmaxf(m.x, __shfl_xor(m.x, 32, 64)); m.y = fmaxf(m.y, __shfl_xor(m.y, 32, 64));
        m.z = fmaxf(m.z, __shfl_xor(m.z, 32, 64)); m.w = fmaxf(m.w, __shfl_xor(m.w, 32, 64));

        const float inv = 1.0f / 128.0f;
        float4 a = make_float4(s.x * inv, s.y * inv, s.z * inv, s.w * inv);
        float* fb = feat + (size_t)b * 2 * HW_ + hw;
        if (lane < 32) *reinterpret_cast<float4*>(fb)       = a;   // avg plane
        else           *reinterpret_cast<float4*>(fb + HW_) = m;   // max plane

        float vals[4];
        vals[0] = a.x + a.y + a.z + a.w;
        vals[1] = a.x*a.x + a.y*a.y + a.z*a.z + a.w*a.w;
        vals[2] = m.x + m.y + m.z + m.w;
        vals[3] = m.x*m.x + m.y*m.y + m.z*m.z + m.w*m.w;
#pragma unroll
        for (int i = 0; i < 4; ++i) {        // both halves hold identical values -> 0.5x
            float v = wave_sum(vals[i]);
            if (lane == 0) red[wid] = v;
            __syncthreads();
            if (threadIdx.x == 0)
                atomicAdd(stats + i, 0.5f * (red[0] + red[1] + red[2] + red[3]));
            __syncthreads();
        }
    }
    gbar(bar, NBLK);

    // ---------------- Phase 2: BN1 affine + 7x7x2 conv + BN2 stats ----------------
    if (threadIdx.x < 98) w_s[threadIdx.x] = cw[threadIdx.x];
    if (threadIdx.x < 2) {
        const float invn = 1.0f / (float)NPIX;
        int c = threadIdx.x;
        float mean = stat_ld(stats + 2 * c) * invn;
        float var  = stat_ld(stats + 2 * c + 1) * invn - mean * mean;
        float sc   = g1[c] / sqrtf(var + EPSF);
        sc_s[c] = sc;
        sh_s[c] = be1[c] - mean * sc;
    }
    __syncthreads();

    float acc0 = 0.f, acc1 = 0.f, acc2 = 0.f, acc3 = 0.f;
    if (tid < 131072) {                      // 4 output pixels each
        int b  = tid >> 12;
        int pg = tid & 4095;
        int h  = pg >> 5;
        int w4 = (pg & 31) << 2;
        const float* fb = feat + (size_t)b * 2 * HW_;
#pragma unroll
        for (int c = 0; c < 2; ++c) {
            float sc = sc_s[c], sh = sh_s[c];
            const float* fc = fb + c * HW_;
#pragma unroll
            for (int kh = 0; kh < 7; ++kh) {
                int hh = h + kh - 3;
                if ((unsigned)hh >= 128u) continue;
                const float* row = fc + hh * 128;
                float v[10];
#pragma unroll
                for (int i = 0; i < 10; ++i) {
                    int ww = w4 - 3 + i;
                    v[i] = ((unsigned)ww < 128u) ? row[ww] * sc + sh : 0.f;
                }
#pragma unroll
                for (int kw = 0; kw < 7; ++kw) {
                    float wt = w_s[c * 49 + kh * 7 + kw];
                    acc0 += v[kw]     * wt;
                    acc1 += v[kw + 1] * wt;
                    acc2 += v[kw + 2] * wt;
                    acc3 += v[kw + 3] * wt;
                }
            }
        }
        *reinterpret_cast<float4*>(convout + (size_t)b * HW_ + h * 128 + w4) =
            make_float4(acc0, acc1, acc2, acc3);
    }
    {
        float v = wave_sum(acc0 + acc1 + acc2 + acc3);   // idle threads contribute 0
        if (lane == 0) red[wid] = v;
        __syncthreads();
        if (threadIdx.x == 0) atomicAdd(stats + 4, red[0] + red[1] + red[2] + red[3]);
        __syncthreads();
        v = wave_sum(acc0*acc0 + acc1*acc1 + acc2*acc2 + acc3*acc3);
        if (lane == 0) red[wid] = v;
        __syncthreads();
        if (threadIdx.x == 0) atomicAdd(stats + 5, red[0] + red[1] + red[2] + red[3]);
    }
    gbar(bar, 2u * NBLK);

    // ---------------- Phase 3: out = sigmoid(BN2(conv)) * x ----------------
    // Reversed b sweep (freshest L3 lines of x first); sigmoid hoisted: att is
    // per-(b,hw), reused for both channel halves (c = clo and clo+64).
    {
        const float invn = 1.0f / (float)NPIX;
        float mean = stat_ld(stats + 4) * invn;
        float var  = stat_ld(stats + 5) * invn - mean * mean;
        float s    = g2[0] / sqrtf(var + EPSF);
        float sh   = be2[0] - mean * s;

        int hwq = (tid & 4095) << 2;         // fixed float4 pixel group
        int clo = (tid >> 12) & 63;          // low 6 bits of channel

        for (int b = B_ - 1; b >= 0; --b) {
            float cvx = convout[(size_t)b * HW_ + hwq];
            float cv_[4];
            *reinterpret_cast<float4*>(cv_) =
                *reinterpret_cast<const float4*>(convout + (size_t)b * HW_ + hwq);
            float att[4];
#pragma unroll
            for (int i = 0; i < 4; ++i)
                att[i] = 1.f / (1.f + __expf(-(cv_[i] * s + sh)));
            (void)cvx;
#pragma unroll
            for (int ch = 1; ch >= 0; --ch) {
                int c = ch * 64 + clo;
                size_t xi = ((size_t)(b * 128 + c)) * HW_ + hwq;
                float4 xv = *reinterpret_cast<const float4*>(x + xi);
                *reinterpret_cast<float4*>(out + xi) =
                    make_float4(xv.x * att[0], xv.y * att[1], xv.z * att[2], xv.w * att[3]);
            }
        }
    }
}

extern "C" void kernel_launch(void* const* d_in, const int* in_sizes, int n_in,
                              void* d_out, int out_size, void* d_ws, size_t ws_size,
                              hipStream_t stream) {
    const float* x  = (const float*)d_in[0];
    const float* cw = (const float*)d_in[1];
    const float* g1 = (const float*)d_in[2];
    const float* b1 = (const float*)d_in[3];
    const float* g2 = (const float*)d_in[4];
    const float* b2 = (const float*)d_in[5];
    float* out = (float*)d_out;

    char* ws = (char*)d_ws;
    float*    feat    = (float*)ws;                          // 4 MiB: [B][2][HW]
    float*    convout = (float*)(ws + 4u * 1024 * 1024);     // 2 MiB: [B][HW]
    float*    stats   = (float*)(ws + 6u * 1024 * 1024);     // 8 floats
    unsigned* bar     = (unsigned*)(ws + 6u * 1024 * 1024 + 64);  // barrier counter

    // ws is NOT re-poisoned between replays: zero stats + barrier every call.
    (void)hipMemsetAsync(stats, 0, 128, stream);
    k_fused<<<NBLK, 256, 0, stream>>>(x, cw, g1, b1, g2, b2,
                                      feat, convout, stats, bar, out);
}

// Round 8
// 240.594 us; speedup vs baseline: 4.4093x; 4.4093x over previous
//
#include <hip/hip_runtime.h>
#include <math.h>

#define B_    32
#define C_    128
#define HW_   16384          // 128*128
#define NPIX  524288         // B_*HW_
#define EPSF  1e-5f

typedef float vfloat4 __attribute__((ext_vector_type(4)));  // native vec for nontemporal builtin

__device__ __forceinline__ float wave_sum(float v) {
#pragma unroll
    for (int off = 32; off > 0; off >>= 1) v += __shfl_down(v, off, 64);
    return v;
}

// Kernel 1: per-pixel channel mean/max over C=128, channel loop split 4-way
// across 16-lane subgroups (sub s handles channels [32s,32s+32); combine via
// shfl_xor 16 then 32). 2048 blocks = 8192 waves: half the per-thread chain
// of the 2-way version, 2x the TLP, for latency hiding on the strided reads.
__global__ __launch_bounds__(256) void k_reduce(const float* __restrict__ x,
                                                float* __restrict__ feat,
                                                float* __restrict__ stats) {
    int lane = threadIdx.x & 63, wid = threadIdx.x >> 6;
    int sub  = lane >> 4;                                   // 0..3
    int pg   = (blockIdx.x * 4 + wid) * 16 + (lane & 15);   // float4-pixel group, 131072 total
    int b    = pg >> 12;
    int hw   = (pg & 4095) << 2;
    int ch0  = sub * 32;

    const float4* xp = reinterpret_cast<const float4*>(
        x + (size_t)b * C_ * HW_ + (size_t)ch0 * HW_ + hw);
    float4 s = make_float4(0.f, 0.f, 0.f, 0.f);
    float4 m = make_float4(-INFINITY, -INFINITY, -INFINITY, -INFINITY);
#pragma unroll 8
    for (int c = 0; c < 32; ++c) {
        float4 v = xp[(size_t)c * (HW_ / 4)];
        s.x += v.x; s.y += v.y; s.z += v.z; s.w += v.w;
        m.x = fmaxf(m.x, v.x); m.y = fmaxf(m.y, v.y);
        m.z = fmaxf(m.z, v.z); m.w = fmaxf(m.w, v.w);
    }
    // combine the 4 channel-subsets (lanes with equal (lane&15) share a pixel)
#pragma unroll
    for (int off = 16; off <= 32; off <<= 1) {
        s.x += __shfl_xor(s.x, off, 64); s.y += __shfl_xor(s.y, off, 64);
        s.z += __shfl_xor(s.z, off, 64); s.w += __shfl_xor(s.w, off, 64);
        m.x = fmaxf(m.x, __shfl_xor(m.x, off, 64)); m.y = fmaxf(m.y, __shfl_xor(m.y, off, 64));
        m.z = fmaxf(m.z, __shfl_xor(m.z, off, 64)); m.w = fmaxf(m.w, __shfl_xor(m.w, off, 64));
    }

    const float inv = 1.0f / 128.0f;
    float4 a = make_float4(s.x * inv, s.y * inv, s.z * inv, s.w * inv);
    float* fb = feat + (size_t)b * 2 * HW_ + hw;
    if (sub == 0) *reinterpret_cast<float4*>(fb)       = a;   // avg plane
    if (sub == 1) *reinterpret_cast<float4*>(fb + HW_) = m;   // max plane

    // stats (each pixel's value duplicated in 4 subgroups -> scale by 0.25)
    float vals[4];
    vals[0] = a.x + a.y + a.z + a.w;
    vals[1] = a.x*a.x + a.y*a.y + a.z*a.z + a.w*a.w;
    vals[2] = m.x + m.y + m.z + m.w;
    vals[3] = m.x*m.x + m.y*m.y + m.z*m.z + m.w*m.w;

    __shared__ float red[4];
#pragma unroll
    for (int i = 0; i < 4; ++i) {
        float v = wave_sum(vals[i]);
        if (lane == 0) red[wid] = v;
        __syncthreads();
        if (threadIdx.x == 0)
            atomicAdd(stats + i, 0.25f * (red[0] + red[1] + red[2] + red[3]));
        __syncthreads();
    }
}

// Kernel 2: BN1 affine fused into operand load (OOB contributes 0 post-BN,
// matching pad-after-BN) + 7x7x2 conv, 4 output pixels per thread with
// row-reuse (10-float row serves 4 overlapping 7-tap windows). BN2 stats.
__global__ __launch_bounds__(256) void k_conv(const float* __restrict__ feat,
                                              const float* __restrict__ cw,
                                              const float* __restrict__ g1,
                                              const float* __restrict__ be1,
                                              float* __restrict__ convout,
                                              float* __restrict__ stats) {
    __shared__ float w_s[98];
    __shared__ float sc_s[2], sh_s[2];
    if (threadIdx.x < 98) w_s[threadIdx.x] = cw[threadIdx.x];
    if (threadIdx.x < 2) {
        const float invn = 1.0f / (float)NPIX;
        int c = threadIdx.x;
        float mean = stats[2 * c] * invn;
        float var  = stats[2 * c + 1] * invn - mean * mean;
        float sc   = g1[c] / sqrtf(var + EPSF);
        sc_s[c] = sc;
        sh_s[c] = be1[c] - mean * sc;
    }
    __syncthreads();

    int t  = blockIdx.x * 256 + threadIdx.x;   // 131072 threads, 4 pixels each
    int b  = t >> 12;
    int pg = t & 4095;
    int h  = pg >> 5;
    int w4 = (pg & 31) << 2;                   // output col base (0,4,...,124)
    const float* fb = feat + (size_t)b * 2 * HW_;

    float acc0 = 0.f, acc1 = 0.f, acc2 = 0.f, acc3 = 0.f;
#pragma unroll
    for (int c = 0; c < 2; ++c) {
        float sc = sc_s[c], sh = sh_s[c];
        const float* fc = fb + c * HW_;
#pragma unroll
        for (int kh = 0; kh < 7; ++kh) {
            int hh = h + kh - 3;
            if ((unsigned)hh >= 128u) continue;
            const float* row = fc + hh * 128;
            float v[10];
#pragma unroll
            for (int i = 0; i < 10; ++i) {
                int ww = w4 - 3 + i;
                v[i] = ((unsigned)ww < 128u) ? row[ww] * sc + sh : 0.f;
            }
#pragma unroll
            for (int kw = 0; kw < 7; ++kw) {
                float wt = w_s[c * 49 + kh * 7 + kw];
                acc0 += v[kw]     * wt;
                acc1 += v[kw + 1] * wt;
                acc2 += v[kw + 2] * wt;
                acc3 += v[kw + 3] * wt;
            }
        }
    }
    *reinterpret_cast<float4*>(convout + (size_t)b * HW_ + h * 128 + w4) =
        make_float4(acc0, acc1, acc2, acc3);

    __shared__ float red[4];
    int lane = threadIdx.x & 63, wid = threadIdx.x >> 6;
    float v = wave_sum(acc0 + acc1 + acc2 + acc3);
    if (lane == 0) red[wid] = v;
    __syncthreads();
    if (threadIdx.x == 0) atomicAdd(stats + 4, red[0] + red[1] + red[2] + red[3]);
    __syncthreads();
    v = wave_sum(acc0*acc0 + acc1*acc1 + acc2*acc2 + acc3*acc3);
    if (lane == 0) red[wid] = v;
    __syncthreads();
    if (threadIdx.x == 0) atomicAdd(stats + 5, red[0] + red[1] + red[2] + red[3]);
}

// Kernel 3: att = sigmoid(BN2(conv)); out = att * x. Max-TLP shape (1 float4
// per thread, 16.7M threads). Reversed block order (freshest L3 lines of x
// first) + nontemporal out stores.
__global__ __launch_bounds__(256) void k_apply(const float* __restrict__ x,
                                               const float* __restrict__ convout,
                                               const float* __restrict__ g2,
                                               const float* __restrict__ be2,
                                               const float* __restrict__ stats,
                                               float* __restrict__ out) {
    int t  = (gridDim.x - 1 - blockIdx.x) * 256 + threadIdx.x;  // reverse traversal
    int hw = (t & 4095) << 2;
    int c  = (t >> 12) & 127;
    int b  = t >> 19;

    const float invn = 1.0f / (float)NPIX;
    float mean = stats[4] * invn;
    float var  = stats[5] * invn - mean * mean;
    float s    = g2[0] / sqrtf(var + EPSF);
    float sh   = be2[0] - mean * s;

    float4 cv = *reinterpret_cast<const float4*>(convout + b * HW_ + hw);
    float4 att;
    att.x = 1.f / (1.f + __expf(-(cv.x * s + sh)));
    att.y = 1.f / (1.f + __expf(-(cv.y * s + sh)));
    att.z = 1.f / (1.f + __expf(-(cv.z * s + sh)));
    att.w = 1.f / (1.f + __expf(-(cv.w * s + sh)));

    size_t xi = ((size_t)(b * 128 + c)) * HW_ + hw;
    float4 xv = *reinterpret_cast<const float4*>(x + xi);
    vfloat4 o = { xv.x * att.x, xv.y * att.y, xv.z * att.z, xv.w * att.w };
    __builtin_nontemporal_store(o, reinterpret_cast<vfloat4*>(out + xi));
}

extern "C" void kernel_launch(void* const* d_in, const int* in_sizes, int n_in,
                              void* d_out, int out_size, void* d_ws, size_t ws_size,
                              hipStream_t stream) {
    const float* x  = (const float*)d_in[0];
    const float* cw = (const float*)d_in[1];
    const float* g1 = (const float*)d_in[2];
    const float* b1 = (const float*)d_in[3];
    const float* g2 = (const float*)d_in[4];
    const float* b2 = (const float*)d_in[5];
    float* out = (float*)d_out;

    char* ws = (char*)d_ws;
    float* feat    = (float*)ws;                          // 4 MiB: [B][2][HW]
    float* convout = (float*)(ws + 4u * 1024 * 1024);     // 2 MiB: [B][HW]
    float* stats   = (float*)(ws + 6u * 1024 * 1024);     // 8 floats

    (void)hipMemsetAsync(stats, 0, 8 * sizeof(float), stream);  // ws is NOT re-poisoned; must zero every call
    k_reduce<<<2048,  256, 0, stream>>>(x, feat, stats);
    k_conv  <<<512,   256, 0, stream>>>(feat, cw, g1, b1, convout, stats);
    k_apply <<<65536, 256, 0, stream>>>(x, convout, g2, b2, stats, out);
}

// Round 9
// 198.280 us; speedup vs baseline: 5.3503x; 1.2134x over previous
//
#include <hip/hip_runtime.h>
#include <math.h>

#define B_    32
#define C_    128
#define HW_   16384          // 128*128
#define NPIX  524288         // B_*HW_
#define EPSF  1e-5f

__device__ __forceinline__ float wave_sum(float v) {
#pragma unroll
    for (int off = 32; off > 0; off >>= 1) v += __shfl_down(v, off, 64);
    return v;
}

// Kernel 1 (round-5 exact, best known): per-pixel channel mean/max over C=128,
// channel loop split 2-way across wave halves (512B segments per half), combine
// via shfl_xor 32. Emits feat[B][2][HW], accumulates BN1 stats via atomics.
__global__ __launch_bounds__(256) void k_reduce(const float* __restrict__ x,
                                                float* __restrict__ feat,
                                                float* __restrict__ stats) {
    int lane = threadIdx.x & 63, wid = threadIdx.x >> 6;
    int pg   = (blockIdx.x * 4 + wid) * 32 + (lane & 31);  // float4-pixel group, 131072 total
    int b    = pg >> 12;
    int hw   = (pg & 4095) << 2;
    int ch0  = (lane >> 5) * 64;                           // 0 or 64

    const float4* xp = reinterpret_cast<const float4*>(
        x + (size_t)b * C_ * HW_ + (size_t)ch0 * HW_ + hw);
    float4 s = make_float4(0.f, 0.f, 0.f, 0.f);
    float4 m = make_float4(-INFINITY, -INFINITY, -INFINITY, -INFINITY);
#pragma unroll 8
    for (int c = 0; c < 64; ++c) {
        float4 v = xp[(size_t)c * (HW_ / 4)];
        s.x += v.x; s.y += v.y; s.z += v.z; s.w += v.w;
        m.x = fmaxf(m.x, v.x); m.y = fmaxf(m.y, v.y);
        m.z = fmaxf(m.z, v.z); m.w = fmaxf(m.w, v.w);
    }
    s.x += __shfl_xor(s.x, 32, 64); s.y += __shfl_xor(s.y, 32, 64);
    s.z += __shfl_xor(s.z, 32, 64); s.w += __shfl_xor(s.w, 32, 64);
    m.x = fmaxf(m.x, __shfl_xor(m.x, 32, 64)); m.y = fmaxf(m.y, __shfl_xor(m.y, 32, 64));
    m.z = fmaxf(m.z, __shfl_xor(m.z, 32, 64)); m.w = fmaxf(m.w, __shfl_xor(m.w, 32, 64));

    const float inv = 1.0f / 128.0f;
    float4 a = make_float4(s.x * inv, s.y * inv, s.z * inv, s.w * inv);
    float* fb = feat + (size_t)b * 2 * HW_ + hw;
    if (lane < 32) *reinterpret_cast<float4*>(fb)       = a;   // avg plane
    else           *reinterpret_cast<float4*>(fb + HW_) = m;   // max plane

    float vals[4];
    vals[0] = a.x + a.y + a.z + a.w;
    vals[1] = a.x*a.x + a.y*a.y + a.z*a.z + a.w*a.w;
    vals[2] = m.x + m.y + m.z + m.w;
    vals[3] = m.x*m.x + m.y*m.y + m.z*m.z + m.w*m.w;

    __shared__ float red[4];
#pragma unroll
    for (int i = 0; i < 4; ++i) {        // halves duplicate -> 0.5x
        float v = wave_sum(vals[i]);
        if (lane == 0) red[wid] = v;
        __syncthreads();
        if (threadIdx.x == 0)
            atomicAdd(stats + i, 0.5f * (red[0] + red[1] + red[2] + red[3]));
        __syncthreads();
    }
}

// Kernel 2 (round-5 exact): BN1 affine fused into operand load (OOB = 0
// post-BN, matching pad-after-BN) + 7x7x2 conv, 4 output pixels/thread with
// row-reuse. BN2 stats.
__global__ __launch_bounds__(256) void k_conv(const float* __restrict__ feat,
                                              const float* __restrict__ cw,
                                              const float* __restrict__ g1,
                                              const float* __restrict__ be1,
                                              float* __restrict__ convout,
                                              float* __restrict__ stats) {
    __shared__ float w_s[98];
    __shared__ float sc_s[2], sh_s[2];
    if (threadIdx.x < 98) w_s[threadIdx.x] = cw[threadIdx.x];
    if (threadIdx.x < 2) {
        const float invn = 1.0f / (float)NPIX;
        int c = threadIdx.x;
        float mean = stats[2 * c] * invn;
        float var  = stats[2 * c + 1] * invn - mean * mean;
        float sc   = g1[c] / sqrtf(var + EPSF);
        sc_s[c] = sc;
        sh_s[c] = be1[c] - mean * sc;
    }
    __syncthreads();

    int t  = blockIdx.x * 256 + threadIdx.x;   // 131072 threads, 4 pixels each
    int b  = t >> 12;
    int pg = t & 4095;
    int h  = pg >> 5;
    int w4 = (pg & 31) << 2;                   // output col base (0,4,...,124)
    const float* fb = feat + (size_t)b * 2 * HW_;

    float acc0 = 0.f, acc1 = 0.f, acc2 = 0.f, acc3 = 0.f;
#pragma unroll
    for (int c = 0; c < 2; ++c) {
        float sc = sc_s[c], sh = sh_s[c];
        const float* fc = fb + c * HW_;
#pragma unroll
        for (int kh = 0; kh < 7; ++kh) {
            int hh = h + kh - 3;
            if ((unsigned)hh >= 128u) continue;
            const float* row = fc + hh * 128;
            float v[10];
#pragma unroll
            for (int i = 0; i < 10; ++i) {
                int ww = w4 - 3 + i;
                v[i] = ((unsigned)ww < 128u) ? row[ww] * sc + sh : 0.f;
            }
#pragma unroll
            for (int kw = 0; kw < 7; ++kw) {
                float wt = w_s[c * 49 + kh * 7 + kw];
                acc0 += v[kw]     * wt;
                acc1 += v[kw + 1] * wt;
                acc2 += v[kw + 2] * wt;
                acc3 += v[kw + 3] * wt;
            }
        }
    }
    *reinterpret_cast<float4*>(convout + (size_t)b * HW_ + h * 128 + w4) =
        make_float4(acc0, acc1, acc2, acc3);

    __shared__ float red[4];
    int lane = threadIdx.x & 63, wid = threadIdx.x >> 6;
    float v = wave_sum(acc0 + acc1 + acc2 + acc3);
    if (lane == 0) red[wid] = v;
    __syncthreads();
    if (threadIdx.x == 0) atomicAdd(stats + 4, red[0] + red[1] + red[2] + red[3]);
    __syncthreads();
    v = wave_sum(acc0*acc0 + acc1*acc1 + acc2*acc2 + acc3*acc3);
    if (lane == 0) red[wid] = v;
    __syncthreads();
    if (threadIdx.x == 0) atomicAdd(stats + 5, red[0] + red[1] + red[2] + red[3]);
}

// Kernel 3: att = sigmoid(BN2(conv)); out = att * x. Reversed block order
// (tail of x is L3-freshest after k_reduce's forward sweep). SINGLE CHANGE vs
// round 5: PLAIN stores instead of nontemporal — round-7 fused kernel (plain
// stores, reversed) showed FETCH=267MB (x re-read fully L3-hit), suggesting
// plain streaming writes don't displace read lines while nt-stores don't help.
__global__ __launch_bounds__(256) void k_apply(const float* __restrict__ x,
                                               const float* __restrict__ convout,
                                               const float* __restrict__ g2,
                                               const float* __restrict__ be2,
                                               const float* __restrict__ stats,
                                               float* __restrict__ out) {
    int t  = (gridDim.x - 1 - blockIdx.x) * 256 + threadIdx.x;  // reverse traversal
    int hw = (t & 4095) << 2;
    int c  = (t >> 12) & 127;
    int b  = t >> 19;

    const float invn = 1.0f / (float)NPIX;
    float mean = stats[4] * invn;
    float var  = stats[5] * invn - mean * mean;
    float s    = g2[0] / sqrtf(var + EPSF);
    float sh   = be2[0] - mean * s;

    float4 cv = *reinterpret_cast<const float4*>(convout + b * HW_ + hw);
    float4 att;
    att.x = 1.f / (1.f + __expf(-(cv.x * s + sh)));
    att.y = 1.f / (1.f + __expf(-(cv.y * s + sh)));
    att.z = 1.f / (1.f + __expf(-(cv.z * s + sh)));
    att.w = 1.f / (1.f + __expf(-(cv.w * s + sh)));

    size_t xi = ((size_t)(b * 128 + c)) * HW_ + hw;
    float4 xv = *reinterpret_cast<const float4*>(x + xi);
    *reinterpret_cast<float4*>(out + xi) =
        make_float4(xv.x * att.x, xv.y * att.y, xv.z * att.z, xv.w * att.w);
}

extern "C" void kernel_launch(void* const* d_in, const int* in_sizes, int n_in,
                              void* d_out, int out_size, void* d_ws, size_t ws_size,
                              hipStream_t stream) {
    const float* x  = (const float*)d_in[0];
    const float* cw = (const float*)d_in[1];
    const float* g1 = (const float*)d_in[2];
    const float* b1 = (const float*)d_in[3];
    const float* g2 = (const float*)d_in[4];
    const float* b2 = (const float*)d_in[5];
    float* out = (float*)d_out;

    char* ws = (char*)d_ws;
    float* feat    = (float*)ws;                          // 4 MiB: [B][2][HW]
    float* convout = (float*)(ws + 4u * 1024 * 1024);     // 2 MiB: [B][HW]
    float* stats   = (float*)(ws + 6u * 1024 * 1024);     // 8 floats

    (void)hipMemsetAsync(stats, 0, 8 * sizeof(float), stream);  // ws is NOT re-poisoned; must zero every call
    k_reduce<<<1024,  256, 0, stream>>>(x, feat, stats);
    k_conv  <<<512,   256, 0, stream>>>(feat, cw, g1, b1, convout, stats);
    k_apply <<<65536, 256, 0, stream>>>(x, convout, g2, b2, stats, out);
}

// Round 10
// 170.268 us; speedup vs baseline: 6.2305x; 1.1645x over previous
//
#include <hip/hip_runtime.h>
#include <math.h>

#define B_    32
#define C_    128
#define HW_   16384          // 128*128
#define NPIX  524288         // B_*HW_
#define EPSF  1e-5f

typedef float vfloat4 __attribute__((ext_vector_type(4)));  // native vec for nontemporal builtins

__device__ __forceinline__ float wave_sum(float v) {
#pragma unroll
    for (int off = 32; off > 0; off >>= 1) v += __shfl_down(v, off, 64);
    return v;
}

// Kernel 1 (R5 core): per-pixel channel mean/max over C=128, channel loop
// split 2-way across wave halves, combine via shfl_xor 32. Emits feat[B][2][HW].
// CHANGES: BN1 stats -> deterministic per-block partials pp[4][1024] (no
// atomics, no host memset); block 0 zeroes the BN2 accumulators for k_conv.
__global__ __launch_bounds__(256) void k_reduce(const float* __restrict__ x,
                                                float* __restrict__ feat,
                                                float* __restrict__ pp,
                                                float* __restrict__ bn2) {
    if (blockIdx.x == 0 && threadIdx.x < 2) bn2[threadIdx.x] = 0.f;  // ws not re-poisoned; zero every call

    int lane = threadIdx.x & 63, wid = threadIdx.x >> 6;
    int pg   = (blockIdx.x * 4 + wid) * 32 + (lane & 31);  // float4-pixel group, 131072 total
    int b    = pg >> 12;
    int hw   = (pg & 4095) << 2;
    int ch0  = (lane >> 5) * 64;                           // 0 or 64

    const float4* xp = reinterpret_cast<const float4*>(
        x + (size_t)b * C_ * HW_ + (size_t)ch0 * HW_ + hw);
    float4 s = make_float4(0.f, 0.f, 0.f, 0.f);
    float4 m = make_float4(-INFINITY, -INFINITY, -INFINITY, -INFINITY);
#pragma unroll 8
    for (int c = 0; c < 64; ++c) {
        float4 v = xp[(size_t)c * (HW_ / 4)];
        s.x += v.x; s.y += v.y; s.z += v.z; s.w += v.w;
        m.x = fmaxf(m.x, v.x); m.y = fmaxf(m.y, v.y);
        m.z = fmaxf(m.z, v.z); m.w = fmaxf(m.w, v.w);
    }
    s.x += __shfl_xor(s.x, 32, 64); s.y += __shfl_xor(s.y, 32, 64);
    s.z += __shfl_xor(s.z, 32, 64); s.w += __shfl_xor(s.w, 32, 64);
    m.x = fmaxf(m.x, __shfl_xor(m.x, 32, 64)); m.y = fmaxf(m.y, __shfl_xor(m.y, 32, 64));
    m.z = fmaxf(m.z, __shfl_xor(m.z, 32, 64)); m.w = fmaxf(m.w, __shfl_xor(m.w, 32, 64));

    const float inv = 1.0f / 128.0f;
    float4 a = make_float4(s.x * inv, s.y * inv, s.z * inv, s.w * inv);
    float* fb = feat + (size_t)b * 2 * HW_ + hw;
    if (lane < 32) *reinterpret_cast<float4*>(fb)       = a;   // avg plane
    else           *reinterpret_cast<float4*>(fb + HW_) = m;   // max plane

    float vals[4];
    vals[0] = a.x + a.y + a.z + a.w;
    vals[1] = a.x*a.x + a.y*a.y + a.z*a.z + a.w*a.w;
    vals[2] = m.x + m.y + m.z + m.w;
    vals[3] = m.x*m.x + m.y*m.y + m.z*m.z + m.w*m.w;

    __shared__ float red[4];
#pragma unroll
    for (int i = 0; i < 4; ++i) {        // halves duplicate -> 0.5x
        float v = wave_sum(vals[i]);
        if (lane == 0) red[wid] = v;
        __syncthreads();
        if (threadIdx.x == 0)
            pp[i * 1024 + blockIdx.x] = 0.5f * (red[0] + red[1] + red[2] + red[3]);
        __syncthreads();
    }
}

// Kernel 2: prologue deterministically reduces the 4x1024 BN1 partials (each
// block redundantly; 64KB L2-hit reads), then BN1-affine-fused 7x7x2 conv
// (OOB = 0 post-BN, matching pad-after-BN), 4 output pixels/thread with
// row-reuse. BN2 stats via atomics into bn2[2] (zeroed by k_reduce block 0).
__global__ __launch_bounds__(256) void k_conv(const float* __restrict__ feat,
                                              const float* __restrict__ cw,
                                              const float* __restrict__ g1,
                                              const float* __restrict__ be1,
                                              const float* __restrict__ pp,
                                              float* __restrict__ convout,
                                              float* __restrict__ bn2) {
    __shared__ float w_s[98];
    __shared__ float sc_s[2], sh_s[2];
    __shared__ float red4[4][4];
    int lane = threadIdx.x & 63, wid = threadIdx.x >> 6;

    if (threadIdx.x < 98) w_s[threadIdx.x] = cw[threadIdx.x];
#pragma unroll
    for (int i = 0; i < 4; ++i) {
        const float* p = pp + i * 1024 + threadIdx.x;
        float a = p[0] + p[256] + p[512] + p[768];
        a = wave_sum(a);
        if (lane == 0) red4[i][wid] = a;
    }
    __syncthreads();
    if (threadIdx.x < 2) {
        const float invn = 1.0f / (float)NPIX;
        int c = threadIdx.x;
        float S = red4[2*c][0] + red4[2*c][1] + red4[2*c][2] + red4[2*c][3];
        float Q = red4[2*c+1][0] + red4[2*c+1][1] + red4[2*c+1][2] + red4[2*c+1][3];
        float mean = S * invn;
        float var  = Q * invn - mean * mean;
        float sc   = g1[c] / sqrtf(var + EPSF);
        sc_s[c] = sc;
        sh_s[c] = be1[c] - mean * sc;
    }
    __syncthreads();

    int t  = blockIdx.x * 256 + threadIdx.x;   // 131072 threads, 4 pixels each
    int b  = t >> 12;
    int pg = t & 4095;
    int h  = pg >> 5;
    int w4 = (pg & 31) << 2;                   // output col base (0,4,...,124)
    const float* fb = feat + (size_t)b * 2 * HW_;

    float acc0 = 0.f, acc1 = 0.f, acc2 = 0.f, acc3 = 0.f;
#pragma unroll
    for (int c = 0; c < 2; ++c) {
        float sc = sc_s[c], sh = sh_s[c];
        const float* fc = fb + c * HW_;
#pragma unroll
        for (int kh = 0; kh < 7; ++kh) {
            int hh = h + kh - 3;
            if ((unsigned)hh >= 128u) continue;
            const float* row = fc + hh * 128;
            float v[10];
#pragma unroll
            for (int i = 0; i < 10; ++i) {
                int ww = w4 - 3 + i;
                v[i] = ((unsigned)ww < 128u) ? row[ww] * sc + sh : 0.f;
            }
#pragma unroll
            for (int kw = 0; kw < 7; ++kw) {
                float wt = w_s[c * 49 + kh * 7 + kw];
                acc0 += v[kw]     * wt;
                acc1 += v[kw + 1] * wt;
                acc2 += v[kw + 2] * wt;
                acc3 += v[kw + 3] * wt;
            }
        }
    }
    *reinterpret_cast<float4*>(convout + (size_t)b * HW_ + h * 128 + w4) =
        make_float4(acc0, acc1, acc2, acc3);

    __shared__ float red[4];
    float v = wave_sum(acc0 + acc1 + acc2 + acc3);
    if (lane == 0) red[wid] = v;
    __syncthreads();
    if (threadIdx.x == 0) atomicAdd(bn2 + 0, red[0] + red[1] + red[2] + red[3]);
    __syncthreads();
    v = wave_sum(acc0*acc0 + acc1*acc1 + acc2*acc2 + acc3*acc3);
    if (lane == 0) red[wid] = v;
    __syncthreads();
    if (threadIdx.x == 0) atomicAdd(bn2 + 1, red[0] + red[1] + red[2] + red[3]);
}

// Kernel 3: att = sigmoid(BN2(conv)); out = att * x. CHANGES: each thread
// handles BOTH channel halves (c=clo, clo+64) of its (b,hw) -> convout read
// and sigmoid computed once per 2 channels, 2-deep load/store ILP. Reversed
// block order; x via nontemporal loads (misses don't evict resident lines),
// out via nontemporal stores (R5 best-known).
__global__ __launch_bounds__(256) void k_apply(const float* __restrict__ x,
                                               const float* __restrict__ convout,
                                               const float* __restrict__ g2,
                                               const float* __restrict__ be2,
                                               const float* __restrict__ bn2,
                                               float* __restrict__ out) {
    int t   = (gridDim.x - 1 - blockIdx.x) * 256 + threadIdx.x;  // 8,388,608 threads
    int hw  = (t & 4095) << 2;
    int clo = (t >> 12) & 63;
    int b   = t >> 18;

    const float invn = 1.0f / (float)NPIX;
    float mean = bn2[0] * invn;
    float var  = bn2[1] * invn - mean * mean;
    float s    = g2[0] / sqrtf(var + EPSF);
    float sh   = be2[0] - mean * s;

    float4 cv = *reinterpret_cast<const float4*>(convout + (size_t)b * HW_ + hw);
    float att0 = 1.f / (1.f + __expf(-(cv.x * s + sh)));
    float att1 = 1.f / (1.f + __expf(-(cv.y * s + sh)));
    float att2 = 1.f / (1.f + __expf(-(cv.z * s + sh)));
    float att3 = 1.f / (1.f + __expf(-(cv.w * s + sh)));

    size_t xi0 = ((size_t)(b * 128 + clo)) * HW_ + hw;
    size_t xi1 = xi0 + (size_t)64 * HW_;
    vfloat4 x0 = __builtin_nontemporal_load(reinterpret_cast<const vfloat4*>(x + xi0));
    vfloat4 x1 = __builtin_nontemporal_load(reinterpret_cast<const vfloat4*>(x + xi1));
    vfloat4 o0 = { x0.x * att0, x0.y * att1, x0.z * att2, x0.w * att3 };
    vfloat4 o1 = { x1.x * att0, x1.y * att1, x1.z * att2, x1.w * att3 };
    __builtin_nontemporal_store(o0, reinterpret_cast<vfloat4*>(out + xi0));
    __builtin_nontemporal_store(o1, reinterpret_cast<vfloat4*>(out + xi1));
}

extern "C" void kernel_launch(void* const* d_in, const int* in_sizes, int n_in,
                              void* d_out, int out_size, void* d_ws, size_t ws_size,
                              hipStream_t stream) {
    const float* x  = (const float*)d_in[0];
    const float* cw = (const float*)d_in[1];
    const float* g1 = (const float*)d_in[2];
    const float* b1 = (const float*)d_in[3];
    const float* g2 = (const float*)d_in[4];
    const float* b2 = (const float*)d_in[5];
    float* out = (float*)d_out;

    char* ws = (char*)d_ws;
    float* feat    = (float*)ws;                              // 4 MiB: [B][2][HW]
    float* convout = (float*)(ws + 4u * 1024 * 1024);         // 2 MiB: [B][HW]
    float* pp      = (float*)(ws + 6u * 1024 * 1024);         // 16 KiB: BN1 partials [4][1024]
    float* bn2     = (float*)(ws + 6u * 1024 * 1024 + 65536); // 2 floats: BN2 accumulators

    // No memset dispatch: pp fully rewritten by k_reduce each call; bn2 zeroed
    // by k_reduce block 0 before k_conv's atomics (stream-ordered).
    k_reduce<<<1024,  256, 0, stream>>>(x, feat, pp, bn2);
    k_conv  <<<512,   256, 0, stream>>>(feat, cw, g1, b1, pp, convout, bn2);
    k_apply <<<32768, 256, 0, stream>>>(x, convout, g2, b2, bn2, out);
}

// Round 11
// 169.297 us; speedup vs baseline: 6.2662x; 1.0057x over previous
//
#include <hip/hip_runtime.h>
#include <math.h>

#define B_    32
#define C_    128
#define HW_   16384          // 128*128
#define NPIX  524288         // B_*HW_
#define EPSF  1e-5f

typedef float vfloat4 __attribute__((ext_vector_type(4)));  // native vec for nontemporal builtins

__device__ __forceinline__ float wave_sum(float v) {
#pragma unroll
    for (int off = 32; off > 0; off >>= 1) v += __shfl_down(v, off, 64);
    return v;
}

// Kernel 1 (R10 exact): per-pixel channel mean/max over C=128, channel loop
// split 2-way across wave halves, combine via shfl_xor 32. Emits feat[B][2][HW].
// BN1 stats as deterministic per-block partials pp[4][1024] (no atomics, no
// host memset); block 0 zeroes the BN2 accumulators for k_conv.
__global__ __launch_bounds__(256) void k_reduce(const float* __restrict__ x,
                                                float* __restrict__ feat,
                                                float* __restrict__ pp,
                                                float* __restrict__ bn2) {
    if (blockIdx.x == 0 && threadIdx.x < 2) bn2[threadIdx.x] = 0.f;  // ws not re-poisoned; zero every call

    int lane = threadIdx.x & 63, wid = threadIdx.x >> 6;
    int pg   = (blockIdx.x * 4 + wid) * 32 + (lane & 31);  // float4-pixel group, 131072 total
    int b    = pg >> 12;
    int hw   = (pg & 4095) << 2;
    int ch0  = (lane >> 5) * 64;                           // 0 or 64

    const float4* xp = reinterpret_cast<const float4*>(
        x + (size_t)b * C_ * HW_ + (size_t)ch0 * HW_ + hw);
    float4 s = make_float4(0.f, 0.f, 0.f, 0.f);
    float4 m = make_float4(-INFINITY, -INFINITY, -INFINITY, -INFINITY);
#pragma unroll 8
    for (int c = 0; c < 64; ++c) {
        float4 v = xp[(size_t)c * (HW_ / 4)];
        s.x += v.x; s.y += v.y; s.z += v.z; s.w += v.w;
        m.x = fmaxf(m.x, v.x); m.y = fmaxf(m.y, v.y);
        m.z = fmaxf(m.z, v.z); m.w = fmaxf(m.w, v.w);
    }
    s.x += __shfl_xor(s.x, 32, 64); s.y += __shfl_xor(s.y, 32, 64);
    s.z += __shfl_xor(s.z, 32, 64); s.w += __shfl_xor(s.w, 32, 64);
    m.x = fmaxf(m.x, __shfl_xor(m.x, 32, 64)); m.y = fmaxf(m.y, __shfl_xor(m.y, 32, 64));
    m.z = fmaxf(m.z, __shfl_xor(m.z, 32, 64)); m.w = fmaxf(m.w, __shfl_xor(m.w, 32, 64));

    const float inv = 1.0f / 128.0f;
    float4 a = make_float4(s.x * inv, s.y * inv, s.z * inv, s.w * inv);
    float* fb = feat + (size_t)b * 2 * HW_ + hw;
    if (lane < 32) *reinterpret_cast<float4*>(fb)       = a;   // avg plane
    else           *reinterpret_cast<float4*>(fb + HW_) = m;   // max plane

    float vals[4];
    vals[0] = a.x + a.y + a.z + a.w;
    vals[1] = a.x*a.x + a.y*a.y + a.z*a.z + a.w*a.w;
    vals[2] = m.x + m.y + m.z + m.w;
    vals[3] = m.x*m.x + m.y*m.y + m.z*m.z + m.w*m.w;

    __shared__ float red[4];
#pragma unroll
    for (int i = 0; i < 4; ++i) {        // halves duplicate -> 0.5x
        float v = wave_sum(vals[i]);
        if (lane == 0) red[wid] = v;
        __syncthreads();
        if (threadIdx.x == 0)
            pp[i * 1024 + blockIdx.x] = 0.5f * (red[0] + red[1] + red[2] + red[3]);
        __syncthreads();
    }
}

// Kernel 2 (R10 exact): prologue reduces the 4x1024 BN1 partials per block,
// then BN1-affine-fused 7x7x2 conv (OOB = 0 post-BN), 4 output pixels/thread
// with row-reuse. BN2 stats via atomics into bn2[2].
__global__ __launch_bounds__(256) void k_conv(const float* __restrict__ feat,
                                              const float* __restrict__ cw,
                                              const float* __restrict__ g1,
                                              const float* __restrict__ be1,
                                              const float* __restrict__ pp,
                                              float* __restrict__ convout,
                                              float* __restrict__ bn2) {
    __shared__ float w_s[98];
    __shared__ float sc_s[2], sh_s[2];
    __shared__ float red4[4][4];
    int lane = threadIdx.x & 63, wid = threadIdx.x >> 6;

    if (threadIdx.x < 98) w_s[threadIdx.x] = cw[threadIdx.x];
#pragma unroll
    for (int i = 0; i < 4; ++i) {
        const float* p = pp + i * 1024 + threadIdx.x;
        float a = p[0] + p[256] + p[512] + p[768];
        a = wave_sum(a);
        if (lane == 0) red4[i][wid] = a;
    }
    __syncthreads();
    if (threadIdx.x < 2) {
        const float invn = 1.0f / (float)NPIX;
        int c = threadIdx.x;
        float S = red4[2*c][0] + red4[2*c][1] + red4[2*c][2] + red4[2*c][3];
        float Q = red4[2*c+1][0] + red4[2*c+1][1] + red4[2*c+1][2] + red4[2*c+1][3];
        float mean = S * invn;
        float var  = Q * invn - mean * mean;
        float sc   = g1[c] / sqrtf(var + EPSF);
        sc_s[c] = sc;
        sh_s[c] = be1[c] - mean * sc;
    }
    __syncthreads();

    int t  = blockIdx.x * 256 + threadIdx.x;   // 131072 threads, 4 pixels each
    int b  = t >> 12;
    int pg = t & 4095;
    int h  = pg >> 5;
    int w4 = (pg & 31) << 2;                   // output col base (0,4,...,124)
    const float* fb = feat + (size_t)b * 2 * HW_;

    float acc0 = 0.f, acc1 = 0.f, acc2 = 0.f, acc3 = 0.f;
#pragma unroll
    for (int c = 0; c < 2; ++c) {
        float sc = sc_s[c], sh = sh_s[c];
        const float* fc = fb + c * HW_;
#pragma unroll
        for (int kh = 0; kh < 7; ++kh) {
            int hh = h + kh - 3;
            if ((unsigned)hh >= 128u) continue;
            const float* row = fc + hh * 128;
            float v[10];
#pragma unroll
            for (int i = 0; i < 10; ++i) {
                int ww = w4 - 3 + i;
                v[i] = ((unsigned)ww < 128u) ? row[ww] * sc + sh : 0.f;
            }
#pragma unroll
            for (int kw = 0; kw < 7; ++kw) {
                float wt = w_s[c * 49 + kh * 7 + kw];
                acc0 += v[kw]     * wt;
                acc1 += v[kw + 1] * wt;
                acc2 += v[kw + 2] * wt;
                acc3 += v[kw + 3] * wt;
            }
        }
    }
    *reinterpret_cast<float4*>(convout + (size_t)b * HW_ + h * 128 + w4) =
        make_float4(acc0, acc1, acc2, acc3);

    __shared__ float red[4];
    float v = wave_sum(acc0 + acc1 + acc2 + acc3);
    if (lane == 0) red[wid] = v;
    __syncthreads();
    if (threadIdx.x == 0) atomicAdd(bn2 + 0, red[0] + red[1] + red[2] + red[3]);
    __syncthreads();
    v = wave_sum(acc0*acc0 + acc1*acc1 + acc2*acc2 + acc3*acc3);
    if (lane == 0) red[wid] = v;
    __syncthreads();
    if (threadIdx.x == 0) atomicAdd(bn2 + 1, red[0] + red[1] + red[2] + red[3]);
}

// Kernel 3: att = sigmoid(BN2(conv)); out = att * x. CHANGE vs R10: 4-way
// channel ILP — each thread handles c = clo, clo+32, clo+64, clo+96 of its
// (b,hw): 4 independent nt-load/nt-store pairs in flight, one convout read +
// one sigmoid quad per 4 channels. Reversed block order retained.
__global__ __launch_bounds__(256) void k_apply(const float* __restrict__ x,
                                               const float* __restrict__ convout,
                                               const float* __restrict__ g2,
                                               const float* __restrict__ be2,
                                               const float* __restrict__ bn2,
                                               float* __restrict__ out) {
    int t   = (gridDim.x - 1 - blockIdx.x) * 256 + threadIdx.x;  // 4,194,304 threads
    int hw  = (t & 4095) << 2;
    int clo = (t >> 12) & 31;
    int b   = t >> 17;

    const float invn = 1.0f / (float)NPIX;
    float mean = bn2[0] * invn;
    float var  = bn2[1] * invn - mean * mean;
    float s    = g2[0] / sqrtf(var + EPSF);
    float sh   = be2[0] - mean * s;

    float4 cv = *reinterpret_cast<const float4*>(convout + (size_t)b * HW_ + hw);
    float att0 = 1.f / (1.f + __expf(-(cv.x * s + sh)));
    float att1 = 1.f / (1.f + __expf(-(cv.y * s + sh)));
    float att2 = 1.f / (1.f + __expf(-(cv.z * s + sh)));
    float att3 = 1.f / (1.f + __expf(-(cv.w * s + sh)));

    size_t xbase = ((size_t)(b * 128 + clo)) * HW_ + hw;
    const size_t cstep = (size_t)32 * HW_;
    vfloat4 xv[4];
#pragma unroll
    for (int k = 0; k < 4; ++k)
        xv[k] = __builtin_nontemporal_load(
            reinterpret_cast<const vfloat4*>(x + xbase + k * cstep));
#pragma unroll
    for (int k = 0; k < 4; ++k) {
        vfloat4 o = { xv[k].x * att0, xv[k].y * att1, xv[k].z * att2, xv[k].w * att3 };
        __builtin_nontemporal_store(o, reinterpret_cast<vfloat4*>(out + xbase + k * cstep));
    }
}

extern "C" void kernel_launch(void* const* d_in, const int* in_sizes, int n_in,
                              void* d_out, int out_size, void* d_ws, size_t ws_size,
                              hipStream_t stream) {
    const float* x  = (const float*)d_in[0];
    const float* cw = (const float*)d_in[1];
    const float* g1 = (const float*)d_in[2];
    const float* b1 = (const float*)d_in[3];
    const float* g2 = (const float*)d_in[4];
    const float* b2 = (const float*)d_in[5];
    float* out = (float*)d_out;

    char* ws = (char*)d_ws;
    float* feat    = (float*)ws;                              // 4 MiB: [B][2][HW]
    float* convout = (float*)(ws + 4u * 1024 * 1024);         // 2 MiB: [B][HW]
    float* pp      = (float*)(ws + 6u * 1024 * 1024);         // 16 KiB: BN1 partials [4][1024]
    float* bn2     = (float*)(ws + 6u * 1024 * 1024 + 65536); // 2 floats: BN2 accumulators

    // No memset dispatch: pp fully rewritten by k_reduce each call; bn2 zeroed
    // by k_reduce block 0 before k_conv's atomics (stream-ordered).
    k_reduce<<<1024,  256, 0, stream>>>(x, feat, pp, bn2);
    k_conv  <<<512,   256, 0, stream>>>(feat, cw, g1, b1, pp, convout, bn2);
    k_apply <<<16384, 256, 0, stream>>>(x, convout, g2, b2, bn2, out);
}